// Round 1
// baseline (349.304 us; speedup 1.0000x reference)
//
#include <hip/hip_runtime.h>
#include <hip/hip_bf16.h>

// FastGRNN 2-layer (SRNN2). T=2048, B=256, D=32, H0=H1=64, O=35, brick=32.
// Layer 0: 16384 seqs x 32 steps (D=32 -> H=64). Layer 1: 256 seqs x 64 steps.
// fp32 VALU implementation (no fp32 MFMA on CDNA4). Scratch: last0 = 64*256*64 f32 = 4MB in d_ws.

#define NB    64    // num bricks
#define BS    32    // brick size (time steps, layer 0)
#define BATCH 256
#define D0    32
#define H     64
#define OUTD  35

__device__ __forceinline__ float sigm(float x) {
    return 1.0f / (1.0f + __expf(-x));
}
__device__ __forceinline__ float tanh_safe(float x) {
    float a = fabsf(x);
    float e = __expf(-2.0f * a);
    float m = (1.0f - e) / (1.0f + e);
    return copysignf(m, x);
}

// Layer 0: block = 512 threads (8 waves). Each block: 64 sequences (one brick slice),
// wave w owns hidden units [8w, 8w+8). lane = sequence within block.
__global__ __launch_bounds__(512) void l0_kernel(
    const float* __restrict__ x,     // [T=2048][B=256][D=32]
    const float* __restrict__ W,     // [32][64]
    const float* __restrict__ U,     // [64][64]
    const float* __restrict__ bg,    // [64]
    const float* __restrict__ bu,    // [64]
    const float* __restrict__ zeta,  // [1]
    const float* __restrict__ nu,    // [1]
    float* __restrict__ last0)       // [NB*BATCH][H] = [16384][64]
{
    __shared__ float h_s[H][64];   // [unit][seq-in-block], stride-1 in seq: conflict-free

    const int lane  = threadIdx.x & 63;
    const int wave  = threadIdx.x >> 6;
    const int j0    = __builtin_amdgcn_readfirstlane(wave << 3);   // wave-uniform unit base
    const int brick = blockIdx.x >> 2;
    const int batch = ((blockIdx.x & 3) << 6) + lane;

    // zero shared h
    for (int i = threadIdx.x; i < H * 64; i += 512) (&h_s[0][0])[i] = 0.0f;

    const float zs = sigm(zeta[0]);
    const float ns = sigm(nu[0]);

    float bgj[8], buj[8];
#pragma unroll
    for (int jj = 0; jj < 8; ++jj) { bgj[jj] = bg[j0 + jj]; buj[jj] = bu[j0 + jj]; }

    float h[8];
#pragma unroll
    for (int jj = 0; jj < 8; ++jj) h[jj] = 0.0f;

    __syncthreads();

#pragma unroll 1
    for (int t = 0; t < BS; ++t) {
        const float* xp = x + ((size_t)((brick * BS + t) * BATCH + batch)) * D0;

        float xr[D0];
#pragma unroll
        for (int q = 0; q < D0 / 4; ++q) {
            float4 v = reinterpret_cast<const float4*>(xp)[q];
            xr[4 * q + 0] = v.x; xr[4 * q + 1] = v.y;
            xr[4 * q + 2] = v.z; xr[4 * q + 3] = v.w;
        }

        float acc[8];
#pragma unroll
        for (int jj = 0; jj < 8; ++jj) acc[jj] = 0.0f;

        // x @ W  (W row d, cols j0..j0+7 are wave-uniform -> scalar loads)
#pragma unroll
        for (int d = 0; d < D0; ++d) {
#pragma unroll
            for (int jj = 0; jj < 8; ++jj)
                acc[jj] = fmaf(xr[d], W[d * H + j0 + jj], acc[jj]);
        }
        // h @ U  (h broadcast from LDS per k; U uniform -> scalar loads)
#pragma unroll
        for (int k = 0; k < H; ++k) {
            float hk = h_s[k][lane];
#pragma unroll
            for (int jj = 0; jj < 8; ++jj)
                acc[jj] = fmaf(hk, U[k * H + j0 + jj], acc[jj]);
        }

        __syncthreads();   // all reads of old h done before overwrite

#pragma unroll
        for (int jj = 0; jj < 8; ++jj) {
            float pre = acc[jj];
            float z = sigm(pre + bgj[jj]);
            float c = tanh_safe(pre + buj[jj]);
            h[jj] = z * h[jj] + (zs * (1.0f - z) + ns) * c;
            h_s[j0 + jj][lane] = h[jj];
        }

        __syncthreads();   // new h visible for next step
    }

    // write last hidden state: last0[(brick*BATCH + batch)*H + j]
    float* outp = last0 + ((size_t)(brick * BATCH + batch)) * H + j0;
    float4 o0 = { h[0], h[1], h[2], h[3] };
    float4 o1 = { h[4], h[5], h[6], h[7] };
    reinterpret_cast<float4*>(outp)[0] = o0;
    reinterpret_cast<float4*>(outp)[1] = o1;
}

// Layer 1 + output projection: 1 wave per batch element. lane = hidden unit.
// Weight columns (W1[:,lane], U1[:,lane]) in VGPRs; input row broadcast (uniform scalar loads);
// h broadcast via LDS.
__global__ __launch_bounds__(64) void l1_kernel(
    const float* __restrict__ last0,  // [NB][BATCH][H]
    const float* __restrict__ W,      // [64][64]
    const float* __restrict__ U,      // [64][64]
    const float* __restrict__ bg,
    const float* __restrict__ bu,
    const float* __restrict__ zeta,
    const float* __restrict__ nu,
    const float* __restrict__ Wout,   // [64][35]
    const float* __restrict__ Bout,   // [35]
    float* __restrict__ out)          // [BATCH][35]
{
    __shared__ float h_s[H];

    const int lane  = threadIdx.x;
    const int batch = blockIdx.x;

    float wcol[2 * H];
#pragma unroll
    for (int k = 0; k < H; ++k) wcol[k] = W[k * H + lane];
#pragma unroll
    for (int k = 0; k < H; ++k) wcol[H + k] = U[k * H + lane];

    const float zs  = sigm(zeta[0]);
    const float ns  = sigm(nu[0]);
    const float bgj = bg[lane];
    const float buj = bu[lane];

    float h = 0.0f;

#pragma unroll 1
    for (int t = 0; t < NB; ++t) {
        h_s[lane] = h;
        __syncthreads();

        const float* ip = last0 + ((size_t)(t * BATCH + batch)) * H;  // uniform -> s_loads
        float acc = 0.0f;
#pragma unroll
        for (int k = 0; k < H; ++k) acc = fmaf(ip[k], wcol[k], acc);
#pragma unroll
        for (int k = 0; k < H; ++k) acc = fmaf(h_s[k], wcol[H + k], acc);

        __syncthreads();   // reads done before next overwrite

        float z = sigm(acc + bgj);
        float c = tanh_safe(acc + buj);
        h = z * h + (zs * (1.0f - z) + ns) * c;
    }

    // output projection: out = h1 @ Wout + Bout
    h_s[lane] = h;
    __syncthreads();
    if (lane < OUTD) {
        float o = Bout[lane];
#pragma unroll
        for (int k = 0; k < H; ++k) o = fmaf(h_s[k], Wout[k * OUTD + lane], o);
        out[batch * OUTD + lane] = o;
    }
}

extern "C" void kernel_launch(void* const* d_in, const int* in_sizes, int n_in,
                              void* d_out, int out_size, void* d_ws, size_t ws_size,
                              hipStream_t stream) {
    const float* x    = (const float*)d_in[0];
    // d_in[1] = brickSize (fixed 32)
    const float* W0   = (const float*)d_in[2];
    const float* U0   = (const float*)d_in[3];
    const float* bg0  = (const float*)d_in[4];
    const float* bu0  = (const float*)d_in[5];
    const float* z0   = (const float*)d_in[6];
    const float* n0   = (const float*)d_in[7];
    const float* W1   = (const float*)d_in[8];
    const float* U1   = (const float*)d_in[9];
    const float* bg1  = (const float*)d_in[10];
    const float* bu1  = (const float*)d_in[11];
    const float* z1   = (const float*)d_in[12];
    const float* n1   = (const float*)d_in[13];
    const float* Wout = (const float*)d_in[14];
    const float* Bout = (const float*)d_in[15];
    float* out = (float*)d_out;

    float* last0 = (float*)d_ws;   // needs NB*BATCH*H*4 = 4 MB of scratch

    l0_kernel<<<256, 512, 0, stream>>>(x, W0, U0, bg0, bu0, z0, n0, last0);
    l1_kernel<<<BATCH, 64, 0, stream>>>(last0, W1, U1, bg1, bu1, z1, n1, Wout, Bout, out);
}

// Round 2
// 254.902 us; speedup vs baseline: 1.3703x; 1.3703x over previous
//
#include <hip/hip_runtime.h>
#include <hip/hip_bf16.h>

// FastGRNN 2-layer (SRNN2). T=2048, B=256, D=32, H0=H1=64, O=35, brick=32.
// Layer 0: 16384 seqs x 32 steps (D=32 -> H=64), fp32 VALU.
//   Block = 1024 thr (16 waves), lane = seq (64 seqs/block), wave owns 4 hidden units.
//   Weights staged in LDS (broadcast b128 reads), h exchanged via double-buffered
//   float4-packed LDS -> 1 barrier/step. 256 blocks = 4096 waves = 4/SIMD.
// Layer 1: 256 seqs x 64 steps. 1 block/seq; 4 waves precompute xW into LDS,
//   wave 0 runs recurrence with U-columns in VGPRs, h broadcast via LDS b128.

#define NB    64
#define BS    32
#define BATCH 256
#define D0    32
#define H     64
#define OUTD  35

__device__ __forceinline__ float sigm(float x) {
    return 1.0f / (1.0f + __expf(-x));
}
__device__ __forceinline__ float tanh_safe(float x) {
    float a = fabsf(x);
    float e = __expf(-2.0f * a);
    float m = (1.0f - e) / (1.0f + e);
    return copysignf(m, x);
}

__global__ __launch_bounds__(1024, 4) void l0_kernel(
    const float* __restrict__ x,     // [2048][256][32]
    const float* __restrict__ W,     // [32][64]
    const float* __restrict__ U,     // [64][64]
    const float* __restrict__ bg,
    const float* __restrict__ bu,
    const float* __restrict__ zeta,
    const float* __restrict__ nu,
    float* __restrict__ last0)       // [64*256][64]
{
    __shared__ float  Wl[D0 * H];          // 8 KB
    __shared__ float  Ul[H * H];           // 16 KB
    __shared__ float4 hq[2][H / 4][64];    // 32 KB, [buf][k/4][seq-in-block]

    const int lane = threadIdx.x & 63;
    const int wave = threadIdx.x >> 6;                              // 0..15
    const int j0   = __builtin_amdgcn_readfirstlane(wave << 2);     // unit base (uniform)
    const int wq   = __builtin_amdgcn_readfirstlane(wave);          // quad index for h write

    const int brick = blockIdx.x >> 2;
    const int batch = ((blockIdx.x & 3) << 6) + lane;

    // stage weights
    for (int i = threadIdx.x; i < D0 * H; i += 1024) Wl[i] = W[i];
    for (int i = threadIdx.x; i < H * H;  i += 1024) Ul[i] = U[i];
    // zero h buffer 0
    {
        int k4 = threadIdx.x >> 6;
        hq[0][k4][lane] = make_float4(0.f, 0.f, 0.f, 0.f);
    }

    const float zs = sigm(zeta[0]);
    const float ns = sigm(nu[0]);
    const float bg0 = bg[j0 + 0], bg1 = bg[j0 + 1], bg2 = bg[j0 + 2], bg3 = bg[j0 + 3];
    const float bu0 = bu[j0 + 0], bu1 = bu[j0 + 1], bu2 = bu[j0 + 2], bu3 = bu[j0 + 3];

    float h0 = 0.f, h1 = 0.f, h2 = 0.f, h3 = 0.f;

    __syncthreads();

#pragma unroll 1
    for (int t = 0; t < BS; ++t) {
        const int cur = t & 1;
        const float* xp = x + ((size_t)((brick * BS + t) * BATCH + batch)) * D0;

        float xr[D0];
#pragma unroll
        for (int q = 0; q < D0 / 4; ++q) {
            float4 v = reinterpret_cast<const float4*>(xp)[q];
            xr[4 * q + 0] = v.x; xr[4 * q + 1] = v.y;
            xr[4 * q + 2] = v.z; xr[4 * q + 3] = v.w;
        }

        float a0 = 0.f, a1 = 0.f, a2 = 0.f, a3 = 0.f;

        // x @ W : broadcast b128 weight reads from LDS
#pragma unroll
        for (int d = 0; d < D0; ++d) {
            float4 wr = *reinterpret_cast<const float4*>(&Wl[d * H + j0]);
            a0 = fmaf(xr[d], wr.x, a0);
            a1 = fmaf(xr[d], wr.y, a1);
            a2 = fmaf(xr[d], wr.z, a2);
            a3 = fmaf(xr[d], wr.w, a3);
        }

        // h @ U : h as float4 per-lane reads, U rows as broadcast b128
#pragma unroll
        for (int k4 = 0; k4 < H / 4; ++k4) {
            float4 hv = hq[cur][k4][lane];
            {
                float4 ur = *reinterpret_cast<const float4*>(&Ul[(4 * k4 + 0) * H + j0]);
                a0 = fmaf(hv.x, ur.x, a0); a1 = fmaf(hv.x, ur.y, a1);
                a2 = fmaf(hv.x, ur.z, a2); a3 = fmaf(hv.x, ur.w, a3);
            }
            {
                float4 ur = *reinterpret_cast<const float4*>(&Ul[(4 * k4 + 1) * H + j0]);
                a0 = fmaf(hv.y, ur.x, a0); a1 = fmaf(hv.y, ur.y, a1);
                a2 = fmaf(hv.y, ur.z, a2); a3 = fmaf(hv.y, ur.w, a3);
            }
            {
                float4 ur = *reinterpret_cast<const float4*>(&Ul[(4 * k4 + 2) * H + j0]);
                a0 = fmaf(hv.z, ur.x, a0); a1 = fmaf(hv.z, ur.y, a1);
                a2 = fmaf(hv.z, ur.z, a2); a3 = fmaf(hv.z, ur.w, a3);
            }
            {
                float4 ur = *reinterpret_cast<const float4*>(&Ul[(4 * k4 + 3) * H + j0]);
                a0 = fmaf(hv.w, ur.x, a0); a1 = fmaf(hv.w, ur.y, a1);
                a2 = fmaf(hv.w, ur.z, a2); a3 = fmaf(hv.w, ur.w, a3);
            }
        }

        // elementwise update (4 units per lane)
        {
            float z, c;
            z = sigm(a0 + bg0); c = tanh_safe(a0 + bu0);
            h0 = z * h0 + (zs * (1.f - z) + ns) * c;
            z = sigm(a1 + bg1); c = tanh_safe(a1 + bu1);
            h1 = z * h1 + (zs * (1.f - z) + ns) * c;
            z = sigm(a2 + bg2); c = tanh_safe(a2 + bu2);
            h2 = z * h2 + (zs * (1.f - z) + ns) * c;
            z = sigm(a3 + bg3); c = tanh_safe(a3 + bu3);
            h3 = z * h3 + (zs * (1.f - z) + ns) * c;
        }

        // write new h into the other buffer; reads of 'cur' all precede this
        // barrier in every wave, so single barrier per step is safe.
        hq[cur ^ 1][wq][lane] = make_float4(h0, h1, h2, h3);
        __syncthreads();
    }

    float* outp = last0 + ((size_t)(brick * BATCH + batch)) * H + j0;
    *reinterpret_cast<float4*>(outp) = make_float4(h0, h1, h2, h3);
}

// Layer 1 + projection: 1 block per batch element, 256 threads (4 waves).
// Waves 0..3 precompute px[t][j] = last0[t,b,:] @ W1[:,j] into LDS, then wave 0
// runs the 64-step recurrence (U columns in VGPRs, h broadcast via LDS b128).
__global__ __launch_bounds__(256, 1) void l1_kernel(
    const float* __restrict__ last0,  // [64][256][64]
    const float* __restrict__ W,      // [64][64]
    const float* __restrict__ U,      // [64][64]
    const float* __restrict__ bg,
    const float* __restrict__ bu,
    const float* __restrict__ zeta,
    const float* __restrict__ nu,
    const float* __restrict__ Wout,   // [64][35]
    const float* __restrict__ Bout,   // [35]
    float* __restrict__ out)          // [256][35]
{
    __shared__ float px[NB][H];   // 16 KB
    __shared__ float hb[H];

    const int lane  = threadIdx.x & 63;
    const int wave  = __builtin_amdgcn_readfirstlane(threadIdx.x >> 6);  // 0..3
    const int batch = blockIdx.x;

    // W1 column for this lane
    float wc[H];
#pragma unroll
    for (int k = 0; k < H; ++k) wc[k] = W[k * H + lane];

    // precompute px: wave w handles t in [16w, 16w+16)
#pragma unroll 1
    for (int t = wave * 16; t < wave * 16 + 16; ++t) {
        const float* ip = last0 + ((size_t)(t * BATCH + batch)) * H;  // uniform -> s_load
        float a = 0.f;
#pragma unroll
        for (int k = 0; k < H; ++k) a = fmaf(ip[k], wc[k], a);
        px[t][lane] = a;
    }
    __syncthreads();
    if (wave != 0) return;

    // recurrence on wave 0
    float uc[H];
#pragma unroll
    for (int k = 0; k < H; ++k) uc[k] = U[k * H + lane];

    const float zs  = sigm(zeta[0]);
    const float ns  = sigm(nu[0]);
    const float bgj = bg[lane];
    const float buj = bu[lane];

    float h = 0.f;
    hb[lane] = 0.f;

#pragma unroll 1
    for (int t = 0; t < NB; ++t) {
        float a = px[t][lane];
#pragma unroll
        for (int q = 0; q < H / 4; ++q) {
            float4 hv = *reinterpret_cast<const float4*>(&hb[4 * q]);  // broadcast
            a = fmaf(hv.x, uc[4 * q + 0], a);
            a = fmaf(hv.y, uc[4 * q + 1], a);
            a = fmaf(hv.z, uc[4 * q + 2], a);
            a = fmaf(hv.w, uc[4 * q + 3], a);
        }
        float z = sigm(a + bgj);
        float c = tanh_safe(a + buj);
        h = z * h + (zs * (1.f - z) + ns) * c;
        hb[lane] = h;   // in-order within wave; lgkmcnt orders next step's reads
    }

    // output projection
    if (lane < OUTD) {
        float o = Bout[lane];
#pragma unroll
        for (int k = 0; k < H; ++k) o = fmaf(hb[k], Wout[k * OUTD + lane], o);
        out[batch * OUTD + lane] = o;
    }
}

extern "C" void kernel_launch(void* const* d_in, const int* in_sizes, int n_in,
                              void* d_out, int out_size, void* d_ws, size_t ws_size,
                              hipStream_t stream) {
    const float* x    = (const float*)d_in[0];
    const float* W0   = (const float*)d_in[2];
    const float* U0   = (const float*)d_in[3];
    const float* bg0  = (const float*)d_in[4];
    const float* bu0  = (const float*)d_in[5];
    const float* z0   = (const float*)d_in[6];
    const float* n0   = (const float*)d_in[7];
    const float* W1   = (const float*)d_in[8];
    const float* U1   = (const float*)d_in[9];
    const float* bg1  = (const float*)d_in[10];
    const float* bu1  = (const float*)d_in[11];
    const float* z1   = (const float*)d_in[12];
    const float* n1   = (const float*)d_in[13];
    const float* Wout = (const float*)d_in[14];
    const float* Bout = (const float*)d_in[15];
    float* out = (float*)d_out;

    float* last0 = (float*)d_ws;   // 4 MB scratch

    l0_kernel<<<256, 1024, 0, stream>>>(x, W0, U0, bg0, bu0, z0, n0, last0);
    l1_kernel<<<BATCH, 256, 0, stream>>>(last0, W1, U1, bg1, bu1, z1, n1, Wout, Bout, out);
}

// Round 3
// 85.721 us; speedup vs baseline: 4.0749x; 2.9736x over previous
//
#include <hip/hip_runtime.h>
#include <hip/hip_bf16.h>

// FastGRNN 2-layer (SRNN2). T=2048, B=256, D=32, H0=H1=64, O=35, brick=32.
// Layer 0 rewritten with bf16 MFMA (fp32 accumulate, fp32 recurrent state):
//   Block = 1024 thr (16 waves) = 4x4 tile grid of 16x16 output tiles over
//   [64 seqs x 64 units]. Weights live in MFMA B-frags (VGPRs, loaded once).
//   Per step: 1 MFMA x@W (K=32) + 2 MFMA h@U (K=64) per wave; h exchanged via
//   double-buffered XOR-swizzled bf16 LDS (conflict-free b128 A-frag reads);
//   one barrier/step; x prefetched 2 steps ahead.
// Layer 1 (≈2 us): unchanged from round 1.

#define NB    64
#define BS    32
#define BATCH 256
#define D0    32
#define H     64
#define OUTD  35

typedef short  bf8   __attribute__((ext_vector_type(8)));   // 8 bf16 (4 VGPRs)
typedef float  f32x4 __attribute__((ext_vector_type(4)));

__device__ __forceinline__ float sigm(float x) {
    return 1.0f / (1.0f + __expf(-x));
}
__device__ __forceinline__ float tanh_safe(float x) {
    float a = fabsf(x);
    float e = __expf(-2.0f * a);
    float m = (1.0f - e) / (1.0f + e);
    return copysignf(m, x);
}
__device__ __forceinline__ short f2bf(float f) {
    __hip_bfloat16 b = __float2bfloat16(f);
    return __builtin_bit_cast(short, b);
}

__global__ __launch_bounds__(1024, 4) void l0_kernel(
    const float* __restrict__ x,     // [2048][256][32]
    const float* __restrict__ W,     // [32][64]
    const float* __restrict__ U,     // [64][64]
    const float* __restrict__ bg,
    const float* __restrict__ bu,
    const float* __restrict__ zeta,
    const float* __restrict__ nu,
    float* __restrict__ last0)       // [64*256][64]
{
    // h as bf16, [buf][seq][unit], unit-bytes XOR-swizzled by ((seq&7)<<4)
    __shared__ unsigned char hb[2][64 * 128];   // 16 KB

    const int tid  = threadIdx.x;
    const int lane = tid & 63;
    const int wave = tid >> 6;
    const int wm   = __builtin_amdgcn_readfirstlane(wave >> 2);   // M-tile 0..3 (seq)
    const int wn   = __builtin_amdgcn_readfirstlane(wave & 3);    // N-tile 0..3 (unit)
    const int l15  = lane & 15;
    const int lg   = lane >> 4;                                   // 0..3

    const int brick     = blockIdx.x >> 2;
    const int batchbase = (blockIdx.x & 3) << 6;

    // zero h buffer 0 (8 KB / 1024 thr = 8 B each)
    *reinterpret_cast<float2*>(&hb[0][tid * 8]) = make_float2(0.f, 0.f);

    // weight B-fragments, loaded once (bf16). k-map: k = 8*lg + j (+32c for U chunk 1)
    bf8 Wb, Ub0, Ub1;
    const int ucol = wn * 16 + l15;
#pragma unroll
    for (int j = 0; j < 8; ++j) Wb[j]  = f2bf(W[(8 * lg + j) * H + ucol]);
#pragma unroll
    for (int j = 0; j < 8; ++j) Ub0[j] = f2bf(U[(8 * lg + j) * H + ucol]);
#pragma unroll
    for (int j = 0; j < 8; ++j) Ub1[j] = f2bf(U[(32 + 8 * lg + j) * H + ucol]);

    const float bgc = bg[ucol], buc = bu[ucol];
    const float zs  = sigm(zeta[0]);
    const float ns  = sigm(nu[0]);

    float hc[4] = {0.f, 0.f, 0.f, 0.f};   // fp32 recurrent state, C-layout

    // x: lane reads 8 consecutive floats X[t][batchbase + wm*16 + l15][8*lg..]
    const float* xbase = x + ((size_t)(brick * BS) * BATCH + batchbase + wm * 16 + l15) * D0 + 8 * lg;
    const size_t xstep = (size_t)BATCH * D0;

    float4 xa0 = reinterpret_cast<const float4*>(xbase)[0];
    float4 xa1 = reinterpret_cast<const float4*>(xbase)[1];
    float4 xn0 = reinterpret_cast<const float4*>(xbase + xstep)[0];
    float4 xn1 = reinterpret_cast<const float4*>(xbase + xstep)[1];

    __syncthreads();

    int cur = 0;
#pragma unroll 1
    for (int t = 0; t < BS; ++t) {
        // prefetch t+2
        float4 p0 = make_float4(0.f, 0.f, 0.f, 0.f), p1 = p0;
        if (t + 2 < BS) {
            p0 = reinterpret_cast<const float4*>(xbase + (size_t)(t + 2) * xstep)[0];
            p1 = reinterpret_cast<const float4*>(xbase + (size_t)(t + 2) * xstep)[1];
        }

        // x A-frag
        bf8 xa;
        xa[0] = f2bf(xa0.x); xa[1] = f2bf(xa0.y); xa[2] = f2bf(xa0.z); xa[3] = f2bf(xa0.w);
        xa[4] = f2bf(xa1.x); xa[5] = f2bf(xa1.y); xa[6] = f2bf(xa1.z); xa[7] = f2bf(xa1.w);

        f32x4 acc = {0.f, 0.f, 0.f, 0.f};
        acc = __builtin_amdgcn_mfma_f32_16x16x32_bf16(xa, Wb, acc, 0, 0, 0);

        // h A-frags from LDS (swizzled, conflict-free b128)
        const int srow = wm * 16 + l15;
        const unsigned char* hr = &hb[cur][srow * 128];
        bf8 ha0 = *reinterpret_cast<const bf8*>(hr + ((16 * lg) ^ ((srow & 7) << 4)));
        bf8 ha1 = *reinterpret_cast<const bf8*>(hr + ((64 + 16 * lg) ^ ((srow & 7) << 4)));
        acc = __builtin_amdgcn_mfma_f32_16x16x32_bf16(ha0, Ub0, acc, 0, 0, 0);
        acc = __builtin_amdgcn_mfma_f32_16x16x32_bf16(ha1, Ub1, acc, 0, 0, 0);

        // elementwise update; C-layout row r -> seq = wm*16 + 4*lg + r, col = ucol
#pragma unroll
        for (int r = 0; r < 4; ++r) {
            float pre = acc[r];
            float z = sigm(pre + bgc);
            float c = tanh_safe(pre + buc);
            hc[r] = z * hc[r] + (zs * (1.f - z) + ns) * c;
        }

        // write new h (bf16) into other buffer
        {
            unsigned char* wb = &hb[cur ^ 1][0];
#pragma unroll
            for (int r = 0; r < 4; ++r) {
                int s   = wm * 16 + 4 * lg + r;
                int off = s * 128 + ((ucol * 2) ^ ((s & 7) << 4));
                *reinterpret_cast<short*>(wb + off) = f2bf(hc[r]);
            }
        }
        __syncthreads();   // writes visible; everyone done reading hb[cur]
        cur ^= 1;
        xa0 = xn0; xa1 = xn1;
        xn0 = p0;  xn1 = p1;
    }

    // write last hidden state (fp32)
    {
        float* op = last0 + ((size_t)(brick * BATCH + batchbase)) * H;
#pragma unroll
        for (int r = 0; r < 4; ++r) {
            int s = wm * 16 + 4 * lg + r;
            op[(size_t)s * H + ucol] = hc[r];
        }
    }
}

// Layer 1 + projection: 1 block per batch element, 256 threads (4 waves).
// Waves 0..3 precompute px[t][j] = last0[t,b,:] @ W1[:,j] into LDS, then wave 0
// runs the 64-step recurrence (U columns in VGPRs, h broadcast via LDS b128).
__global__ __launch_bounds__(256, 1) void l1_kernel(
    const float* __restrict__ last0,  // [64][256][64]
    const float* __restrict__ W,      // [64][64]
    const float* __restrict__ U,      // [64][64]
    const float* __restrict__ bg,
    const float* __restrict__ bu,
    const float* __restrict__ zeta,
    const float* __restrict__ nu,
    const float* __restrict__ Wout,   // [64][35]
    const float* __restrict__ Bout,   // [35]
    float* __restrict__ out)          // [256][35]
{
    __shared__ float px[NB][H];
    __shared__ float hbb[H];

    const int lane  = threadIdx.x & 63;
    const int wave  = __builtin_amdgcn_readfirstlane(threadIdx.x >> 6);
    const int batch = blockIdx.x;

    float wc[H];
#pragma unroll
    for (int k = 0; k < H; ++k) wc[k] = W[k * H + lane];

#pragma unroll 1
    for (int t = wave * 16; t < wave * 16 + 16; ++t) {
        const float* ip = last0 + ((size_t)(t * BATCH + batch)) * H;
        float a = 0.f;
#pragma unroll
        for (int k = 0; k < H; ++k) a = fmaf(ip[k], wc[k], a);
        px[t][lane] = a;
    }
    __syncthreads();
    if (wave != 0) return;

    float uc[H];
#pragma unroll
    for (int k = 0; k < H; ++k) uc[k] = U[k * H + lane];

    const float zs  = sigm(zeta[0]);
    const float ns  = sigm(nu[0]);
    const float bgj = bg[lane];
    const float buj = bu[lane];

    float h = 0.f;
    hbb[lane] = 0.f;

#pragma unroll 1
    for (int t = 0; t < NB; ++t) {
        float a = px[t][lane];
#pragma unroll
        for (int q = 0; q < H / 4; ++q) {
            float4 hv = *reinterpret_cast<const float4*>(&hbb[4 * q]);
            a = fmaf(hv.x, uc[4 * q + 0], a);
            a = fmaf(hv.y, uc[4 * q + 1], a);
            a = fmaf(hv.z, uc[4 * q + 2], a);
            a = fmaf(hv.w, uc[4 * q + 3], a);
        }
        float z = sigm(a + bgj);
        float c = tanh_safe(a + buj);
        h = z * h + (zs * (1.f - z) + ns) * c;
        hbb[lane] = h;
    }

    if (lane < OUTD) {
        float o = Bout[lane];
#pragma unroll
        for (int k = 0; k < H; ++k) o = fmaf(hbb[k], Wout[k * OUTD + lane], o);
        out[batch * OUTD + lane] = o;
    }
}

extern "C" void kernel_launch(void* const* d_in, const int* in_sizes, int n_in,
                              void* d_out, int out_size, void* d_ws, size_t ws_size,
                              hipStream_t stream) {
    const float* x    = (const float*)d_in[0];
    const float* W0   = (const float*)d_in[2];
    const float* U0   = (const float*)d_in[3];
    const float* bg0  = (const float*)d_in[4];
    const float* bu0  = (const float*)d_in[5];
    const float* z0   = (const float*)d_in[6];
    const float* n0   = (const float*)d_in[7];
    const float* W1   = (const float*)d_in[8];
    const float* U1   = (const float*)d_in[9];
    const float* bg1  = (const float*)d_in[10];
    const float* bu1  = (const float*)d_in[11];
    const float* z1   = (const float*)d_in[12];
    const float* n1   = (const float*)d_in[13];
    const float* Wout = (const float*)d_in[14];
    const float* Bout = (const float*)d_in[15];
    float* out = (float*)d_out;

    float* last0 = (float*)d_ws;   // 4 MB scratch

    l0_kernel<<<256, 1024, 0, stream>>>(x, W0, U0, bg0, bu0, z0, n0, last0);
    l1_kernel<<<BATCH, 256, 0, stream>>>(last0, W1, U1, bg1, bu1, z1, n1, Wout, Bout, out);
}

// Round 4
// 72.946 us; speedup vs baseline: 4.7885x; 1.1751x over previous
//
#include <hip/hip_runtime.h>
#include <hip/hip_bf16.h>

// FastGRNN 2-layer (SRNN2). T=2048, B=256, D=32, H0=H1=64, O=35, brick=32.
// Layer 0: bf16 MFMA, fp32 accum + fp32 recurrent state.
//   Block = 256 thr (4 waves) handles 16 seqs x 64 units; wave wn owns unit
//   tile [16wn,16wn+16). 1024 blocks = 4 blocks/CU -> barrier domains decouple.
//   Weights in B-frags (VGPRs, loaded once). Per step/wave: 3 mfma_16x16x32,
//   h via double-buffered XOR-swizzled bf16 LDS, 1 barrier/step, x prefetch 2.
// Layer 1: 256 blocks x 4 waves; waves 0-3 precompute xW into LDS (4-acc ILP),
//   wave 0 runs 64-step recurrence (U cols in VGPRs, h b128-broadcast, 4-acc).
// Elementwise uses v_rcp_f32 (~1 ulp) instead of fp32 divide.

#define NB    64
#define BS    32
#define BATCH 256
#define D0    32
#define H     64
#define OUTD  35

typedef short  bf8   __attribute__((ext_vector_type(8)));
typedef float  f32x4 __attribute__((ext_vector_type(4)));

__device__ __forceinline__ float rcp_fast(float x) {
    return __builtin_amdgcn_rcpf(x);
}
__device__ __forceinline__ float sigm(float x) {
    return rcp_fast(1.0f + __expf(-x));
}
__device__ __forceinline__ float tanh_safe(float x) {
    float a = fabsf(x);
    float e = __expf(-2.0f * a);
    float m = (1.0f - e) * rcp_fast(1.0f + e);
    return copysignf(m, x);
}
__device__ __forceinline__ short f2bf(float f) {
    __hip_bfloat16 b = __float2bfloat16(f);
    return __builtin_bit_cast(short, b);
}

__global__ __launch_bounds__(256, 4) void l0_kernel(
    const float* __restrict__ x,     // [2048][256][32]
    const float* __restrict__ W,     // [32][64]
    const float* __restrict__ U,     // [64][64]
    const float* __restrict__ bg,
    const float* __restrict__ bu,
    const float* __restrict__ zeta,
    const float* __restrict__ nu,
    float* __restrict__ last0)       // [64*256][64]
{
    // h bf16, [buf][seq(16)][unit bytes(128)], bytes XOR-swizzled by ((seq&7)<<4)
    __shared__ unsigned char hb[2][16 * 128];   // 4 KB

    const int tid  = threadIdx.x;
    const int lane = tid & 63;
    const int wn   = __builtin_amdgcn_readfirstlane(tid >> 6);   // unit tile 0..3
    const int l15  = lane & 15;
    const int lg   = lane >> 4;                                  // 0..3

    const int brick     = blockIdx.x >> 4;          // 0..63
    const int batchbase = (blockIdx.x & 15) << 4;   // 0..240

    // zero h buffer 0 (2 KB / 256 thr = 8 B each)
    *reinterpret_cast<float2*>(&hb[0][tid * 8]) = make_float2(0.f, 0.f);

    // weight B-frags (loaded once). k-map: k = 8*lg + j (+32 for Ub1)
    bf8 Wb, Ub0, Ub1;
    const int ucol = wn * 16 + l15;
#pragma unroll
    for (int j = 0; j < 8; ++j) Wb[j]  = f2bf(W[(8 * lg + j) * H + ucol]);
#pragma unroll
    for (int j = 0; j < 8; ++j) Ub0[j] = f2bf(U[(8 * lg + j) * H + ucol]);
#pragma unroll
    for (int j = 0; j < 8; ++j) Ub1[j] = f2bf(U[(32 + 8 * lg + j) * H + ucol]);

    const float bgc = bg[ucol], buc = bu[ucol];
    const float zs  = sigm(zeta[0]);
    const float ns  = sigm(nu[0]);

    float hc[4] = {0.f, 0.f, 0.f, 0.f};   // fp32 state, C-layout rows

    // x: lane reads 8 floats X[brick*BS+t][batchbase + l15][8*lg ..]
    const float* xbase = x + ((size_t)(brick * BS) * BATCH + batchbase + l15) * D0 + 8 * lg;
    const size_t xstep = (size_t)BATCH * D0;

    float4 xa0 = reinterpret_cast<const float4*>(xbase)[0];
    float4 xa1 = reinterpret_cast<const float4*>(xbase)[1];
    float4 xn0 = reinterpret_cast<const float4*>(xbase + xstep)[0];
    float4 xn1 = reinterpret_cast<const float4*>(xbase + xstep)[1];

    __syncthreads();

    int cur = 0;
#pragma unroll 1
    for (int t = 0; t < BS; ++t) {
        // prefetch t+2 (clamped address: always valid, no exec-mask dance)
        const int tp = (t + 2 < BS) ? (t + 2) : (BS - 1);
        float4 p0 = reinterpret_cast<const float4*>(xbase + (size_t)tp * xstep)[0];
        float4 p1 = reinterpret_cast<const float4*>(xbase + (size_t)tp * xstep)[1];

        bf8 xa;
        xa[0] = f2bf(xa0.x); xa[1] = f2bf(xa0.y); xa[2] = f2bf(xa0.z); xa[3] = f2bf(xa0.w);
        xa[4] = f2bf(xa1.x); xa[5] = f2bf(xa1.y); xa[6] = f2bf(xa1.z); xa[7] = f2bf(xa1.w);

        f32x4 acc = {0.f, 0.f, 0.f, 0.f};
        acc = __builtin_amdgcn_mfma_f32_16x16x32_bf16(xa, Wb, acc, 0, 0, 0);

        // h A-frags (seq row = l15), swizzled conflict-free b128 reads
        const unsigned char* hr = &hb[cur][l15 * 128];
        const int swz = (l15 & 7) << 4;
        bf8 ha0 = *reinterpret_cast<const bf8*>(hr + ((16 * lg) ^ swz));
        bf8 ha1 = *reinterpret_cast<const bf8*>(hr + ((64 + 16 * lg) ^ swz));
        acc = __builtin_amdgcn_mfma_f32_16x16x32_bf16(ha0, Ub0, acc, 0, 0, 0);
        acc = __builtin_amdgcn_mfma_f32_16x16x32_bf16(ha1, Ub1, acc, 0, 0, 0);

        // elementwise: C row r -> seq = 4*lg + r, col = ucol
#pragma unroll
        for (int r = 0; r < 4; ++r) {
            float pre = acc[r];
            float z = sigm(pre + bgc);
            float c = tanh_safe(pre + buc);
            hc[r] = z * hc[r] + (zs * (1.f - z) + ns) * c;
        }

        // write new h into other buffer
        {
            unsigned char* wb = &hb[cur ^ 1][0];
#pragma unroll
            for (int r = 0; r < 4; ++r) {
                int s   = 4 * lg + r;
                int off = s * 128 + ((ucol * 2) ^ ((s & 7) << 4));
                *reinterpret_cast<short*>(wb + off) = f2bf(hc[r]);
            }
        }
        __syncthreads();
        cur ^= 1;
        xa0 = xn0; xa1 = xn1;
        xn0 = p0;  xn1 = p1;
    }

    // last hidden state (fp32)
    {
        float* op = last0 + ((size_t)(brick * BATCH + batchbase)) * H;
#pragma unroll
        for (int r = 0; r < 4; ++r) {
            int s = 4 * lg + r;
            op[(size_t)s * H + ucol] = hc[r];
        }
    }
}

// Layer 1 + projection.
__global__ __launch_bounds__(256, 1) void l1_kernel(
    const float* __restrict__ last0,  // [64][256][64]
    const float* __restrict__ W,      // [64][64]
    const float* __restrict__ U,      // [64][64]
    const float* __restrict__ bg,
    const float* __restrict__ bu,
    const float* __restrict__ zeta,
    const float* __restrict__ nu,
    const float* __restrict__ Wout,   // [64][35]
    const float* __restrict__ Bout,   // [35]
    float* __restrict__ out)          // [256][35]
{
    __shared__ float px[NB][H];
    __shared__ float hbb[H];

    const int lane  = threadIdx.x & 63;
    const int wave  = __builtin_amdgcn_readfirstlane(threadIdx.x >> 6);
    const int batch = blockIdx.x;

    float wc[H];
#pragma unroll
    for (int k = 0; k < H; ++k) wc[k] = W[k * H + lane];

    // precompute px[t][j] = last0[t,b,:] @ W1[:,j]; 4 accumulators for ILP
#pragma unroll 1
    for (int t = wave * 16; t < wave * 16 + 16; ++t) {
        const float* ip = last0 + ((size_t)(t * BATCH + batch)) * H;
        float a0 = 0.f, a1 = 0.f, a2 = 0.f, a3 = 0.f;
#pragma unroll
        for (int q = 0; q < H / 4; ++q) {
            a0 = fmaf(ip[4 * q + 0], wc[4 * q + 0], a0);
            a1 = fmaf(ip[4 * q + 1], wc[4 * q + 1], a1);
            a2 = fmaf(ip[4 * q + 2], wc[4 * q + 2], a2);
            a3 = fmaf(ip[4 * q + 3], wc[4 * q + 3], a3);
        }
        px[t][lane] = (a0 + a1) + (a2 + a3);
    }
    __syncthreads();
    if (wave != 0) return;

    float uc[H];
#pragma unroll
    for (int k = 0; k < H; ++k) uc[k] = U[k * H + lane];

    const float zs  = sigm(zeta[0]);
    const float ns  = sigm(nu[0]);
    const float bgj = bg[lane];
    const float buj = bu[lane];

    float h = 0.f;
    hbb[lane] = 0.f;

#pragma unroll 1
    for (int t = 0; t < NB; ++t) {
        float a0 = px[t][lane], a1 = 0.f, a2 = 0.f, a3 = 0.f;
#pragma unroll
        for (int q = 0; q < H / 4; ++q) {
            float4 hv = *reinterpret_cast<const float4*>(&hbb[4 * q]);  // broadcast
            a0 = fmaf(hv.x, uc[4 * q + 0], a0);
            a1 = fmaf(hv.y, uc[4 * q + 1], a1);
            a2 = fmaf(hv.z, uc[4 * q + 2], a2);
            a3 = fmaf(hv.w, uc[4 * q + 3], a3);
        }
        float a = (a0 + a1) + (a2 + a3);
        float z = sigm(a + bgj);
        float c = tanh_safe(a + buj);
        h = z * h + (zs * (1.f - z) + ns) * c;
        hbb[lane] = h;   // same-wave in-order; lgkmcnt orders next step's reads
    }

    if (lane < OUTD) {
        float o = Bout[lane];
#pragma unroll
        for (int k = 0; k < H; ++k) o = fmaf(hbb[k], Wout[k * OUTD + lane], o);
        out[batch * OUTD + lane] = o;
    }
}

extern "C" void kernel_launch(void* const* d_in, const int* in_sizes, int n_in,
                              void* d_out, int out_size, void* d_ws, size_t ws_size,
                              hipStream_t stream) {
    const float* x    = (const float*)d_in[0];
    const float* W0   = (const float*)d_in[2];
    const float* U0   = (const float*)d_in[3];
    const float* bg0  = (const float*)d_in[4];
    const float* bu0  = (const float*)d_in[5];
    const float* z0   = (const float*)d_in[6];
    const float* n0   = (const float*)d_in[7];
    const float* W1   = (const float*)d_in[8];
    const float* U1   = (const float*)d_in[9];
    const float* bg1  = (const float*)d_in[10];
    const float* bu1  = (const float*)d_in[11];
    const float* z1   = (const float*)d_in[12];
    const float* n1   = (const float*)d_in[13];
    const float* Wout = (const float*)d_in[14];
    const float* Bout = (const float*)d_in[15];
    float* out = (float*)d_out;

    float* last0 = (float*)d_ws;   // 4 MB scratch

    l0_kernel<<<1024, 256, 0, stream>>>(x, W0, U0, bg0, bu0, z0, n0, last0);
    l1_kernel<<<BATCH, 256, 0, stream>>>(last0, W1, U1, bg1, bu1, z1, n1, Wout, Bout, out);
}